// Round 1
// baseline (452.478 us; speedup 1.0000x reference)
//
#include <hip/hip_runtime.h>
#include <hip/hip_cooperative_groups.h>

namespace cg = cooperative_groups;

// Problem constants
#define NPTS  32768
#define KNB   16
#define CH    128
#define INNER 512
#define EPS   1e-5f
#define PPB   64               // points per block (fused kernel)
#define NBLK  (NPTS / PPB)     // 512 blocks -> 2 blocks/CU co-resident (coop-safe)

// Workspace layout (float offsets): M[128*128], stats[256] (sum|sumsq)
#define WS_M     0
#define WS_STATS 16384

// Native vector type — __builtin_nontemporal_load requires a real vector.
typedef float f4 __attribute__((ext_vector_type(4)));

// ---------------------------------------------------------------------------
// Kernel 1: M = Wv @ Wo  (128x512 @ 512x128 -> 128x128); block 0 also zeroes
// the stats accumulator (ws is poisoned 0xAA by the harness each iteration).
// ---------------------------------------------------------------------------
__global__ __launch_bounds__(256) void k_wvwo(const float* __restrict__ Wv,
                                              const float* __restrict__ Wo,
                                              float* __restrict__ M,
                                              float* __restrict__ stats) {
    int t  = threadIdx.x;
    if (blockIdx.x == 0) stats[t] = 0.f;     // 256 floats
    int id = blockIdx.x * 256 + t;           // 0..16383
    int c  = id >> 7;
    int cp = id & 127;
    const float* wvr = Wv + c * INNER;
    float a0 = 0.f, a1 = 0.f, a2 = 0.f, a3 = 0.f;
#pragma unroll 4
    for (int i = 0; i < INNER; i += 4) {
        a0 = fmaf(wvr[i + 0], Wo[(i + 0) * CH + cp], a0);
        a1 = fmaf(wvr[i + 1], Wo[(i + 1) * CH + cp], a1);
        a2 = fmaf(wvr[i + 2], Wo[(i + 2) * CH + cp], a2);
        a3 = fmaf(wvr[i + 3], Wo[(i + 3) * CH + cp], a3);
    }
    M[c * CH + cp] = (a0 + a1) + (a2 + a3);
}

// ---------------------------------------------------------------------------
// Kernel 2 (fused, cooperative): per block of 64 points:
//   phase 1: hs[p][c] = sum_k h[n,k,c]   (268 MB streamed NT, coalesced 16B)
//   phase 2: y[p][c'] = hs[p][:] @ M[:,c']  into REGISTERS (not written yet)
//   stats:   block-reduce per-channel sum/sumsq, one atomicAdd per thread
//   grid.sync()
//   norm:    recompute BN coefs from stats (agent-scope loads — per-XCD L2s
//            are not coherent for plain loads), normalize the register
//            accumulators, single NT store of y.
// Saves the k_norm round-trip (33.6 MB) and one kernel launch.
// ---------------------------------------------------------------------------
__global__ __launch_bounds__(256, 2) void k_fused(const float* __restrict__ h,
                                                  const float* __restrict__ Mg,
                                                  float* __restrict__ y,
                                                  float* __restrict__ stats,
                                                  const float* __restrict__ gamma,
                                                  const float* __restrict__ beta) {
    __shared__ f4    hs4[PPB * 32];      // 32 KB: hs[64 pts][128 ch] as float4
    __shared__ float red[4][2][128];     // 4 KB: cross-wave stat reduce
    __shared__ float sa[128], sb[128];   // BN coefficients

    const int t  = threadIdx.x;
    const int n0 = blockIdx.x * PPB;
    const f4* __restrict__ h4 = (const f4*)h;

    // ---- phase 1: k-sum ----
#pragma unroll 2
    for (int j = 0; j < 8; ++j) {
        int pi = t + 256 * j;            // 2048 (point, quad) pairs
        int p  = pi >> 5;
        int c4 = pi & 31;
        size_t base = (size_t)(n0 + p) * (KNB * 32) + c4;   // float4 index
        f4 a = __builtin_nontemporal_load(&h4[base]);
#pragma unroll
        for (int k = 1; k < KNB; ++k) {
            f4 v = __builtin_nontemporal_load(&h4[base + (size_t)k * 32]);
            a += v;
        }
        hs4[p * 32 + c4] = a;
    }
    __syncthreads();

    // ---- phase 2: GEMV  y = hs @ M  (kept in registers) ----
    const int w  = t >> 6;     // wave 0..3
    const int l  = t & 63;     // lane
    const int p0 = w * 16;     // 16 points per wave
    float acc0[16], acc1[16];  // channels l and l+64
#pragma unroll
    for (int p = 0; p < 16; ++p) { acc0[p] = 0.f; acc1[p] = 0.f; }

    for (int cc = 0; cc < 32; ++cc) {
        const int c = 4 * cc;
        float m00 = Mg[(c + 0) * CH + l];
        float m01 = Mg[(c + 1) * CH + l];
        float m02 = Mg[(c + 2) * CH + l];
        float m03 = Mg[(c + 3) * CH + l];
        float m10 = Mg[(c + 0) * CH + 64 + l];
        float m11 = Mg[(c + 1) * CH + 64 + l];
        float m12 = Mg[(c + 2) * CH + 64 + l];
        float m13 = Mg[(c + 3) * CH + 64 + l];
#pragma unroll
        for (int p = 0; p < 16; ++p) {
            f4 hv = hs4[(p0 + p) * 32 + cc];   // LDS broadcast (free)
            acc0[p] = fmaf(hv.x, m00, acc0[p]);
            acc0[p] = fmaf(hv.y, m01, acc0[p]);
            acc0[p] = fmaf(hv.z, m02, acc0[p]);
            acc0[p] = fmaf(hv.w, m03, acc0[p]);
            acc1[p] = fmaf(hv.x, m10, acc1[p]);
            acc1[p] = fmaf(hv.y, m11, acc1[p]);
            acc1[p] = fmaf(hv.z, m12, acc1[p]);
            acc1[p] = fmaf(hv.w, m13, acc1[p]);
        }
    }

    // ---- per-channel stats: block reduce, one atomic per thread ----
    float s0 = 0.f, s1 = 0.f, q0 = 0.f, q1 = 0.f;
#pragma unroll
    for (int p = 0; p < 16; ++p) {
        s0 += acc0[p];  q0 = fmaf(acc0[p], acc0[p], q0);
        s1 += acc1[p];  q1 = fmaf(acc1[p], acc1[p], q1);
    }
    red[w][0][l]      = s0;
    red[w][0][64 + l] = s1;
    red[w][1][l]      = q0;
    red[w][1][64 + l] = q1;
    __syncthreads();
    {
        int s = t >> 7, c = t & 127;
        float v = red[0][s][c] + red[1][s][c] + red[2][s][c] + red[3][s][c];
        atomicAdd(&stats[t], v);   // device-scope by default on gfx950
    }

    // ---- grid-wide barrier: all stats atomics complete & visible ----
    cg::this_grid().sync();

    // ---- BN coefs (redundant per block; stats L2/HBM-hot, tiny) ----
    if (t < 128) {
        float S  = __hip_atomic_load(&stats[t],       __ATOMIC_RELAXED,
                                     __HIP_MEMORY_SCOPE_AGENT);
        float Q  = __hip_atomic_load(&stats[128 + t], __ATOMIC_RELAXED,
                                     __HIP_MEMORY_SCOPE_AGENT);
        float mu  = S * (1.f / NPTS);
        float var = Q * (1.f / NPTS) - mu * mu;   // biased variance
        float a   = gamma[t] * rsqrtf(var + EPS);
        sa[t] = a;
        sb[t] = beta[t] - mu * a;
    }
    __syncthreads();

    // ---- normalize in-register, single NT write of y ----
    float a0 = sa[l], b0 = sb[l], a1 = sa[64 + l], b1 = sb[64 + l];
#pragma unroll
    for (int p = 0; p < 16; ++p) {
        size_t row = (size_t)(n0 + p0 + p) * CH;
        __builtin_nontemporal_store(fmaxf(0.f, fmaf(acc0[p], a0, b0)),
                                    &y[row + l]);
        __builtin_nontemporal_store(fmaxf(0.f, fmaf(acc1[p], a1, b1)),
                                    &y[row + 64 + l]);
    }
}

// ---------------------------------------------------------------------------
// Fallback path (proven 3-kernel structure) in case the cooperative launch is
// rejected by the runtime — keeps the round green no matter what.
// ---------------------------------------------------------------------------
__global__ __launch_bounds__(256) void k_main(const float* __restrict__ h,
                                              const float* __restrict__ Mg,
                                              float* __restrict__ y,
                                              float* __restrict__ stats) {
    __shared__ f4    hs4[32 * 32];
    __shared__ float red[4][2][128];

    const int t  = threadIdx.x;
    const int n0 = blockIdx.x * 32;
    const f4* __restrict__ h4 = (const f4*)h;

#pragma unroll 2
    for (int j = 0; j < 4; ++j) {
        int pi = t + 256 * j;
        int p  = pi >> 5;
        int c4 = pi & 31;
        size_t base = (size_t)(n0 + p) * (KNB * 32) + c4;
        f4 a = __builtin_nontemporal_load(&h4[base]);
#pragma unroll
        for (int k = 1; k < KNB; ++k) {
            f4 v = __builtin_nontemporal_load(&h4[base + (size_t)k * 32]);
            a += v;
        }
        hs4[p * 32 + c4] = a;
    }
    __syncthreads();

    const int w  = t >> 6;
    const int l  = t & 63;
    const int p0 = w * 8;
    float acc0[8] = {0,0,0,0,0,0,0,0};
    float acc1[8] = {0,0,0,0,0,0,0,0};

    for (int cc = 0; cc < 32; ++cc) {
        const int c = 4 * cc;
        float m00 = Mg[(c + 0) * CH + l];
        float m01 = Mg[(c + 1) * CH + l];
        float m02 = Mg[(c + 2) * CH + l];
        float m03 = Mg[(c + 3) * CH + l];
        float m10 = Mg[(c + 0) * CH + 64 + l];
        float m11 = Mg[(c + 1) * CH + 64 + l];
        float m12 = Mg[(c + 2) * CH + 64 + l];
        float m13 = Mg[(c + 3) * CH + 64 + l];
#pragma unroll
        for (int p = 0; p < 8; ++p) {
            f4 hv = hs4[(p0 + p) * 32 + cc];
            acc0[p] = fmaf(hv.x, m00, acc0[p]);
            acc0[p] = fmaf(hv.y, m01, acc0[p]);
            acc0[p] = fmaf(hv.z, m02, acc0[p]);
            acc0[p] = fmaf(hv.w, m03, acc0[p]);
            acc1[p] = fmaf(hv.x, m10, acc1[p]);
            acc1[p] = fmaf(hv.y, m11, acc1[p]);
            acc1[p] = fmaf(hv.z, m12, acc1[p]);
            acc1[p] = fmaf(hv.w, m13, acc1[p]);
        }
    }

    float s0 = 0.f, s1 = 0.f, q0 = 0.f, q1 = 0.f;
#pragma unroll
    for (int p = 0; p < 8; ++p) {
        size_t row = (size_t)(n0 + p0 + p) * CH;
        y[row + l]      = acc0[p];
        y[row + 64 + l] = acc1[p];
        s0 += acc0[p];  q0 = fmaf(acc0[p], acc0[p], q0);
        s1 += acc1[p];  q1 = fmaf(acc1[p], acc1[p], q1);
    }
    red[w][0][l]      = s0;
    red[w][0][64 + l] = s1;
    red[w][1][l]      = q0;
    red[w][1][64 + l] = q1;
    __syncthreads();
    {
        int s = t >> 7, c = t & 127;
        float v = red[0][s][c] + red[1][s][c] + red[2][s][c] + red[3][s][c];
        atomicAdd(&stats[t], v);
    }
}

__global__ __launch_bounds__(256) void k_norm(float* __restrict__ y,
                                              const float* __restrict__ stats,
                                              const float* __restrict__ gamma,
                                              const float* __restrict__ beta) {
    __shared__ float sa[128], sb[128];
    int t = threadIdx.x;
    if (t < 128) {
        float S  = stats[t];
        float Q  = stats[128 + t];
        float mu = S * (1.f / NPTS);
        float var = Q * (1.f / NPTS) - mu * mu;
        float a  = gamma[t] * rsqrtf(var + EPS);
        sa[t] = a;
        sb[t] = beta[t] - mu * a;
    }
    __syncthreads();

    int gid = blockIdx.x * 256 + t;
    f4* y4 = (f4*)y;
    int c0 = (gid & 31) * 4;
    f4 a = { sa[c0], sa[c0 + 1], sa[c0 + 2], sa[c0 + 3] };
    f4 b = { sb[c0], sb[c0 + 1], sb[c0 + 2], sb[c0 + 3] };
#pragma unroll
    for (int i = 0; i < 4; ++i) {
        size_t idx = (size_t)gid + (size_t)i * 262144;
        f4 v = y4[idx];
        v.x = fmaxf(0.f, fmaf(v.x, a.x, b.x));
        v.y = fmaxf(0.f, fmaf(v.y, a.y, b.y));
        v.z = fmaxf(0.f, fmaf(v.z, a.z, b.z));
        v.w = fmaxf(0.f, fmaf(v.w, a.w, b.w));
        y4[idx] = v;
    }
}

// ---------------------------------------------------------------------------
extern "C" void kernel_launch(void* const* d_in, const int* in_sizes, int n_in,
                              void* d_out, int out_size, void* d_ws, size_t ws_size,
                              hipStream_t stream) {
    // inputs: h, x, Wq, Wk, Wv, Wo, bo, gamma, beta
    const float* h     = (const float*)d_in[0];
    const float* Wv    = (const float*)d_in[4];
    const float* Wo    = (const float*)d_in[5];
    const float* gamma = (const float*)d_in[7];
    const float* beta  = (const float*)d_in[8];
    // x, Wq, Wk dead (softmax over singleton dim == 1); bo cancels in BN.

    float* out   = (float*)d_out;
    float* ws    = (float*)d_ws;
    float* M     = ws + WS_M;
    float* stats = ws + WS_STATS;

    k_wvwo<<<64, 256, 0, stream>>>(Wv, Wo, M, stats);

    void* args[] = { (void*)&h, (void*)&M, (void*)&out, (void*)&stats,
                     (void*)&gamma, (void*)&beta };
    hipError_t e = hipLaunchCooperativeKernel((void*)k_fused, dim3(NBLK),
                                              dim3(256), args, 0, stream);
    if (e != hipSuccess) {
        (void)hipGetLastError();   // clear sticky error, take proven path
        k_main<<<1024, 256, 0, stream>>>(h, M, out, stats);
        k_norm<<<1024, 256, 0, stream>>>(out, stats, gamma, beta);
    }
}

// Round 2
// 408.026 us; speedup vs baseline: 1.1089x; 1.1089x over previous
//
#include <hip/hip_runtime.h>

// Problem constants
#define NPTS  32768
#define KNB   16
#define CH    128
#define INNER 512
#define EPS   1e-5f

// Workspace layout (float offsets): M[128*128], stats[256] (sum|sumsq)
#define WS_M     0
#define WS_STATS 16384

// Native vector type — __builtin_nontemporal_load requires a real vector,
// not HIP's struct-wrapped float4.
typedef float f4 __attribute__((ext_vector_type(4)));

// ---------------------------------------------------------------------------
// Kernel 1: M = Wv @ Wo  (128x512 @ 512x128 -> 128x128); block 0 also zeroes
// the stats accumulator (ws is poisoned by the harness each iteration).
// v2: latency-bound fix — 64 blocks was 1 wave/SIMD with a 512-load L2-hit
// chain behind only 4 accumulators. Now 128 blocks, K split 2-way across
// lane pairs (256 loads/thread, 8 accumulators -> 8 independent chains),
// combined with one __shfl_xor. ~2x less serial latency.
// ---------------------------------------------------------------------------
__global__ __launch_bounds__(256) void k_wvwo(const float* __restrict__ Wv,
                                              const float* __restrict__ Wo,
                                              float* __restrict__ M,
                                              float* __restrict__ stats) {
    int t = threadIdx.x;
    if (blockIdx.x == 0) stats[t] = 0.f;     // 256 floats
    int gid  = blockIdx.x * 256 + t;         // 0..32767
    int id   = gid >> 1;                     // output element 0..16383
    int half = gid & 1;                      // K-half
    int c    = id >> 7;
    int cp   = id & 127;
    const float* wvr = Wv + c * INNER + half * 256;
    const float* wor = Wo + (size_t)(half * 256) * CH + cp;
    float a0 = 0.f, a1 = 0.f, a2 = 0.f, a3 = 0.f;
    float a4 = 0.f, a5 = 0.f, a6 = 0.f, a7 = 0.f;
#pragma unroll 4
    for (int i = 0; i < 256; i += 8) {
        a0 = fmaf(wvr[i + 0], wor[(i + 0) * CH], a0);
        a1 = fmaf(wvr[i + 1], wor[(i + 1) * CH], a1);
        a2 = fmaf(wvr[i + 2], wor[(i + 2) * CH], a2);
        a3 = fmaf(wvr[i + 3], wor[(i + 3) * CH], a3);
        a4 = fmaf(wvr[i + 4], wor[(i + 4) * CH], a4);
        a5 = fmaf(wvr[i + 5], wor[(i + 5) * CH], a5);
        a6 = fmaf(wvr[i + 6], wor[(i + 6) * CH], a6);
        a7 = fmaf(wvr[i + 7], wor[(i + 7) * CH], a7);
    }
    float s = ((a0 + a1) + (a2 + a3)) + ((a4 + a5) + (a6 + a7));
    s += __shfl_xor(s, 1);                   // combine the two K-halves
    if (!half) M[c * CH + cp] = s;
}

// ---------------------------------------------------------------------------
// Kernel 2 (main): per block of 32 points:
//   phase 1: hs[p][c] = sum_k h[n,k,c]   (streams 268 MB, coalesced 16B,
//            NON-TEMPORAL: h is touched once; keep y/M resident in L2/L3)
//   phase 2: y[p][c'] = hs[p][:] @ M[:,c']   (M rows L1/L2-hot)
//   epilogue: y -> d_out (unnormalized), per-channel sum/sumsq block-reduced,
//             then ONE device-scope atomicAdd per thread into stats[256].
// ---------------------------------------------------------------------------
__global__ __launch_bounds__(256) void k_main(const float* __restrict__ h,
                                              const float* __restrict__ Mg,
                                              float* __restrict__ y,
                                              float* __restrict__ stats) {
    __shared__ f4    hs4[32 * 32];       // hs[32 pts][128 ch] as float4
    __shared__ float red[4][2][128];     // cross-wave stat reduce

    const int t  = threadIdx.x;
    const int n0 = blockIdx.x * 32;
    const f4* __restrict__ h4 = (const f4*)h;

    // ---- phase 1: k-sum ----
#pragma unroll 2
    for (int j = 0; j < 4; ++j) {
        int pi = t + 256 * j;
        int p  = pi >> 5;          // point within block
        int c4 = pi & 31;          // channel-quad
        size_t base = (size_t)(n0 + p) * (KNB * 32) + c4;   // float4 index
        f4 a = __builtin_nontemporal_load(&h4[base]);
#pragma unroll
        for (int k = 1; k < KNB; ++k) {
            f4 v = __builtin_nontemporal_load(&h4[base + (size_t)k * 32]);
            a += v;
        }
        hs4[p * 32 + c4] = a;
    }
    __syncthreads();

    // ---- phase 2: GEMV  y = hs @ M ----
    const int w  = t >> 6;     // wave 0..3
    const int l  = t & 63;     // lane
    const int p0 = w * 8;      // 8 points per wave
    float acc0[8] = {0,0,0,0,0,0,0,0};   // channel l
    float acc1[8] = {0,0,0,0,0,0,0,0};   // channel l+64

    for (int cc = 0; cc < 32; ++cc) {
        const int c = 4 * cc;
        float m00 = Mg[(c + 0) * CH + l];
        float m01 = Mg[(c + 1) * CH + l];
        float m02 = Mg[(c + 2) * CH + l];
        float m03 = Mg[(c + 3) * CH + l];
        float m10 = Mg[(c + 0) * CH + 64 + l];
        float m11 = Mg[(c + 1) * CH + 64 + l];
        float m12 = Mg[(c + 2) * CH + 64 + l];
        float m13 = Mg[(c + 3) * CH + 64 + l];
#pragma unroll
        for (int p = 0; p < 8; ++p) {
            f4 hv = hs4[(p0 + p) * 32 + cc];   // LDS broadcast (free)
            acc0[p] = fmaf(hv.x, m00, acc0[p]);
            acc0[p] = fmaf(hv.y, m01, acc0[p]);
            acc0[p] = fmaf(hv.z, m02, acc0[p]);
            acc0[p] = fmaf(hv.w, m03, acc0[p]);
            acc1[p] = fmaf(hv.x, m10, acc1[p]);
            acc1[p] = fmaf(hv.y, m11, acc1[p]);
            acc1[p] = fmaf(hv.z, m12, acc1[p]);
            acc1[p] = fmaf(hv.w, m13, acc1[p]);
        }
    }

    // ---- epilogue: write y, block-reduce stats, one atomic per thread ----
    float s0 = 0.f, s1 = 0.f, q0 = 0.f, q1 = 0.f;
#pragma unroll
    for (int p = 0; p < 8; ++p) {
        size_t row = (size_t)(n0 + p0 + p) * CH;
        y[row + l]      = acc0[p];
        y[row + 64 + l] = acc1[p];
        s0 += acc0[p];  q0 = fmaf(acc0[p], acc0[p], q0);
        s1 += acc1[p];  q1 = fmaf(acc1[p], acc1[p], q1);
    }
    red[w][0][l]      = s0;
    red[w][0][64 + l] = s1;
    red[w][1][l]      = q0;
    red[w][1][64 + l] = q1;
    __syncthreads();
    {
        int s = t >> 7, c = t & 127;
        float v = red[0][s][c] + red[1][s][c] + red[2][s][c] + red[3][s][c];
        atomicAdd(&stats[t], v);   // device-scope by default on gfx950
    }
}

// ---------------------------------------------------------------------------
// Kernel 3: normalize + ReLU in-place on d_out. Every block redundantly
// computes the BN coefficients from stats[256] (L2-hot, ~200 cyc) — removes
// the separate latency-bound k_coef launch. y read is L3-hit (just written).
// ---------------------------------------------------------------------------
__global__ __launch_bounds__(256) void k_norm(float* __restrict__ y,
                                              const float* __restrict__ stats,
                                              const float* __restrict__ gamma,
                                              const float* __restrict__ beta) {
    __shared__ float sa[128], sb[128];
    int t = threadIdx.x;
    if (t < 128) {
        float S  = stats[t];
        float Q  = stats[128 + t];
        float mu = S * (1.f / NPTS);
        float var = Q * (1.f / NPTS) - mu * mu;   // biased variance
        float a  = gamma[t] * rsqrtf(var + EPS);
        sa[t] = a;
        sb[t] = beta[t] - mu * a;
    }
    __syncthreads();

    int gid = blockIdx.x * 256 + t;                 // 262144 threads
    f4* y4 = (f4*)y;
    int c0 = (gid & 31) * 4;                        // channel-quad, same every iter
    f4 a = { sa[c0], sa[c0 + 1], sa[c0 + 2], sa[c0 + 3] };
    f4 b = { sb[c0], sb[c0 + 1], sb[c0 + 2], sb[c0 + 3] };
#pragma unroll
    for (int i = 0; i < 4; ++i) {
        size_t idx = (size_t)gid + (size_t)i * 262144;
        f4 v = y4[idx];
        v.x = fmaxf(0.f, fmaf(v.x, a.x, b.x));
        v.y = fmaxf(0.f, fmaf(v.y, a.y, b.y));
        v.z = fmaxf(0.f, fmaf(v.z, a.z, b.z));
        v.w = fmaxf(0.f, fmaf(v.w, a.w, b.w));
        y4[idx] = v;
    }
}

// ---------------------------------------------------------------------------
extern "C" void kernel_launch(void* const* d_in, const int* in_sizes, int n_in,
                              void* d_out, int out_size, void* d_ws, size_t ws_size,
                              hipStream_t stream) {
    // inputs: h, x, Wq, Wk, Wv, Wo, bo, gamma, beta
    const float* h     = (const float*)d_in[0];
    const float* Wv    = (const float*)d_in[4];
    const float* Wo    = (const float*)d_in[5];
    const float* gamma = (const float*)d_in[7];
    const float* beta  = (const float*)d_in[8];
    // x, Wq, Wk dead (softmax over singleton dim == 1); bo cancels in BN.

    float* out   = (float*)d_out;
    float* ws    = (float*)d_ws;
    float* M     = ws + WS_M;
    float* stats = ws + WS_STATS;

    k_wvwo<<<128,  256, 0, stream>>>(Wv, Wo, M, stats);
    k_main<<<1024, 256, 0, stream>>>(h, M, out, stats);
    k_norm<<<1024, 256, 0, stream>>>(out, stats, gamma, beta);
}

// Round 3
// 406.809 us; speedup vs baseline: 1.1123x; 1.0030x over previous
//
#include <hip/hip_runtime.h>

// Problem constants
#define NPTS  32768
#define KNB   16
#define CH    128
#define INNER 512
#define EPS   1e-5f

// Workspace layout (float offsets): M[128*128], stats[256] (sum|sumsq)
#define WS_M     0
#define WS_STATS 16384

// Native vector type — __builtin_nontemporal_load requires a real vector,
// not HIP's struct-wrapped float4.
typedef float f4 __attribute__((ext_vector_type(4)));

// ---------------------------------------------------------------------------
// Kernel 1: M = Wv @ Wo  (128x512 @ 512x128 -> 128x128); block 0 also zeroes
// the stats accumulator (ws is poisoned by the harness each iteration).
// 128 blocks, K split 2-way across lane pairs (256 loads/thread, 8
// accumulators -> 8 independent chains), combined with one __shfl_xor.
// ---------------------------------------------------------------------------
__global__ __launch_bounds__(256) void k_wvwo(const float* __restrict__ Wv,
                                              const float* __restrict__ Wo,
                                              float* __restrict__ M,
                                              float* __restrict__ stats) {
    int t = threadIdx.x;
    if (blockIdx.x == 0) stats[t] = 0.f;     // 256 floats
    int gid  = blockIdx.x * 256 + t;         // 0..32767
    int id   = gid >> 1;                     // output element 0..16383
    int half = gid & 1;                      // K-half
    int c    = id >> 7;
    int cp   = id & 127;
    const float* wvr = Wv + c * INNER + half * 256;
    const float* wor = Wo + (size_t)(half * 256) * CH + cp;
    float a0 = 0.f, a1 = 0.f, a2 = 0.f, a3 = 0.f;
    float a4 = 0.f, a5 = 0.f, a6 = 0.f, a7 = 0.f;
#pragma unroll 4
    for (int i = 0; i < 256; i += 8) {
        a0 = fmaf(wvr[i + 0], wor[(i + 0) * CH], a0);
        a1 = fmaf(wvr[i + 1], wor[(i + 1) * CH], a1);
        a2 = fmaf(wvr[i + 2], wor[(i + 2) * CH], a2);
        a3 = fmaf(wvr[i + 3], wor[(i + 3) * CH], a3);
        a4 = fmaf(wvr[i + 4], wor[(i + 4) * CH], a4);
        a5 = fmaf(wvr[i + 5], wor[(i + 5) * CH], a5);
        a6 = fmaf(wvr[i + 6], wor[(i + 6) * CH], a6);
        a7 = fmaf(wvr[i + 7], wor[(i + 7) * CH], a7);
    }
    float s = ((a0 + a1) + (a2 + a3)) + ((a4 + a5) + (a6 + a7));
    s += __shfl_xor(s, 1);                   // combine the two K-halves
    if (!half) M[c * CH + cp] = s;
}

// ---------------------------------------------------------------------------
// Kernel 2 (main): per block of 16 points (v3: was 32 — 2048 blocks gives
// 8 blocks/CU resident (12 KB LDS, ~48 VGPR) = 32 waves/CU, so the memory
// phase of some blocks overlaps the compute phase of others much more finely,
// and the no-stream-left tail at the end halves):
//   phase 1: hs[p][c] = sum_k h[n,k,c]   (streams 268 MB, coalesced 16B,
//            NON-TEMPORAL: h is touched once; keep y/M resident in L2/L3)
//   phase 2: y[p][c'] = hs[p][:] @ M[:,c']   (M rows L1/L2-hot)
//   epilogue: y -> d_out (unnormalized), per-channel sum/sumsq block-reduced,
//             then ONE device-scope atomicAdd per thread into stats[256].
// ---------------------------------------------------------------------------
__global__ __launch_bounds__(256) void k_main(const float* __restrict__ h,
                                              const float* __restrict__ Mg,
                                              float* __restrict__ y,
                                              float* __restrict__ stats) {
    __shared__ f4    hs4[16 * 32];       // hs[16 pts][128 ch] as float4 (8 KB)
    __shared__ float red[4][2][128];     // cross-wave stat reduce (4 KB)

    const int t  = threadIdx.x;
    const int n0 = blockIdx.x * 16;
    const f4* __restrict__ h4 = (const f4*)h;

    // ---- phase 1: k-sum ----
#pragma unroll
    for (int j = 0; j < 2; ++j) {
        int pi = t + 256 * j;      // 512 (point, quad) pairs
        int p  = pi >> 5;          // point within block
        int c4 = pi & 31;          // channel-quad
        size_t base = (size_t)(n0 + p) * (KNB * 32) + c4;   // float4 index
        f4 a = __builtin_nontemporal_load(&h4[base]);
#pragma unroll
        for (int k = 1; k < KNB; ++k) {
            f4 v = __builtin_nontemporal_load(&h4[base + (size_t)k * 32]);
            a += v;
        }
        hs4[p * 32 + c4] = a;
    }
    __syncthreads();

    // ---- phase 2: GEMV  y = hs @ M ----
    const int w  = t >> 6;     // wave 0..3
    const int l  = t & 63;     // lane
    const int p0 = w * 4;      // 4 points per wave
    float acc0[4] = {0,0,0,0};   // channel l
    float acc1[4] = {0,0,0,0};   // channel l+64

    for (int cc = 0; cc < 32; ++cc) {
        const int c = 4 * cc;
        float m00 = Mg[(c + 0) * CH + l];
        float m01 = Mg[(c + 1) * CH + l];
        float m02 = Mg[(c + 2) * CH + l];
        float m03 = Mg[(c + 3) * CH + l];
        float m10 = Mg[(c + 0) * CH + 64 + l];
        float m11 = Mg[(c + 1) * CH + 64 + l];
        float m12 = Mg[(c + 2) * CH + 64 + l];
        float m13 = Mg[(c + 3) * CH + 64 + l];
#pragma unroll
        for (int p = 0; p < 4; ++p) {
            f4 hv = hs4[(p0 + p) * 32 + cc];   // LDS broadcast (free)
            acc0[p] = fmaf(hv.x, m00, acc0[p]);
            acc0[p] = fmaf(hv.y, m01, acc0[p]);
            acc0[p] = fmaf(hv.z, m02, acc0[p]);
            acc0[p] = fmaf(hv.w, m03, acc0[p]);
            acc1[p] = fmaf(hv.x, m10, acc1[p]);
            acc1[p] = fmaf(hv.y, m11, acc1[p]);
            acc1[p] = fmaf(hv.z, m12, acc1[p]);
            acc1[p] = fmaf(hv.w, m13, acc1[p]);
        }
    }

    // ---- epilogue: write y, block-reduce stats, one atomic per thread ----
    float s0 = 0.f, s1 = 0.f, q0 = 0.f, q1 = 0.f;
#pragma unroll
    for (int p = 0; p < 4; ++p) {
        size_t row = (size_t)(n0 + p0 + p) * CH;
        y[row + l]      = acc0[p];
        y[row + 64 + l] = acc1[p];
        s0 += acc0[p];  q0 = fmaf(acc0[p], acc0[p], q0);
        s1 += acc1[p];  q1 = fmaf(acc1[p], acc1[p], q1);
    }
    red[w][0][l]      = s0;
    red[w][0][64 + l] = s1;
    red[w][1][l]      = q0;
    red[w][1][64 + l] = q1;
    __syncthreads();
    {
        int s = t >> 7, c = t & 127;
        float v = red[0][s][c] + red[1][s][c] + red[2][s][c] + red[3][s][c];
        atomicAdd(&stats[t], v);   // device-scope by default on gfx950
    }
}

// ---------------------------------------------------------------------------
// Kernel 3: normalize + ReLU in-place on d_out. Every block redundantly
// computes the BN coefficients from stats[256] (L2-hot, ~200 cyc) — removes
// the separate latency-bound k_coef launch. y read is L2/L3-hit (just written).
// ---------------------------------------------------------------------------
__global__ __launch_bounds__(256) void k_norm(float* __restrict__ y,
                                              const float* __restrict__ stats,
                                              const float* __restrict__ gamma,
                                              const float* __restrict__ beta) {
    __shared__ float sa[128], sb[128];
    int t = threadIdx.x;
    if (t < 128) {
        float S  = stats[t];
        float Q  = stats[128 + t];
        float mu = S * (1.f / NPTS);
        float var = Q * (1.f / NPTS) - mu * mu;   // biased variance
        float a  = gamma[t] * rsqrtf(var + EPS);
        sa[t] = a;
        sb[t] = beta[t] - mu * a;
    }
    __syncthreads();

    int gid = blockIdx.x * 256 + t;                 // 262144 threads
    f4* y4 = (f4*)y;
    int c0 = (gid & 31) * 4;                        // channel-quad, same every iter
    f4 a = { sa[c0], sa[c0 + 1], sa[c0 + 2], sa[c0 + 3] };
    f4 b = { sb[c0], sb[c0 + 1], sb[c0 + 2], sb[c0 + 3] };
#pragma unroll
    for (int i = 0; i < 4; ++i) {
        size_t idx = (size_t)gid + (size_t)i * 262144;
        f4 v = y4[idx];
        v.x = fmaxf(0.f, fmaf(v.x, a.x, b.x));
        v.y = fmaxf(0.f, fmaf(v.y, a.y, b.y));
        v.z = fmaxf(0.f, fmaf(v.z, a.z, b.z));
        v.w = fmaxf(0.f, fmaf(v.w, a.w, b.w));
        y4[idx] = v;
    }
}

// ---------------------------------------------------------------------------
extern "C" void kernel_launch(void* const* d_in, const int* in_sizes, int n_in,
                              void* d_out, int out_size, void* d_ws, size_t ws_size,
                              hipStream_t stream) {
    // inputs: h, x, Wq, Wk, Wv, Wo, bo, gamma, beta
    const float* h     = (const float*)d_in[0];
    const float* Wv    = (const float*)d_in[4];
    const float* Wo    = (const float*)d_in[5];
    const float* gamma = (const float*)d_in[7];
    const float* beta  = (const float*)d_in[8];
    // x, Wq, Wk dead (softmax over singleton dim == 1); bo cancels in BN.

    float* out   = (float*)d_out;
    float* ws    = (float*)d_ws;
    float* M     = ws + WS_M;
    float* stats = ws + WS_STATS;

    k_wvwo<<<128,  256, 0, stream>>>(Wv, Wo, M, stats);
    k_main<<<2048, 256, 0, stream>>>(h, M, out, stats);
    k_norm<<<1024, 256, 0, stream>>>(out, stats, gamma, beta);
}